// Round 2
// baseline (3829.472 us; speedup 1.0000x reference)
//
#include <hip/hip_runtime.h>

// VanillaRNN: h_{t+1} = tanh(W_hx x_t + W_hh h_t + b_h), T=1024, H=512, B=256.
// R2 design: one batch column per workgroup (256 wgs ~ 256 CUs), no inter-wg sync.
// 256 threads (4 waves = 1 wave/SIMD), 2 rows per thread, waves_per_eu(1,1) so the
// compiler may use up to ~512 unified VGPR+AGPR per thread:
//   - W_hh chunks 0..55  (k in [0,448)) : f16 in registers, 448 regs/thread
//   - W_hh chunks 56..63 (k in [448,512)): f16 in LDS (64 KB), conflict-free reads
//   - h: f16 double-buffered in LDS, read as uniform (broadcast) b128 chunks
// 4 accumulators per row (8 independent FMA chains) so a single wave can issue
// v_dot2_f32_f16 back-to-back at 1 instr / 2 cyc.

#define T_SEQ      1024
#define HID        512
#define NTHREADS   256         // 4 waves; thread owns rows tid and tid+256
#define NCLS       10
#define NCHUNK     64          // 64 chunks x 8 halfs = 512 k
#define REG_CHUNKS 56          // k in [0,448) in registers (448 regs for 2 rows)
#define LDS_CHUNKS 8           // k in [448,512) in LDS (64 KB)

typedef _Float16 half2_t __attribute__((ext_vector_type(2)));

__device__ __forceinline__ unsigned int pack2(float a, float b) {
    half2_t h = {(_Float16)a, (_Float16)b};
    return __builtin_bit_cast(unsigned int, h);
}

__device__ __forceinline__ uint4 pack8(float4 a, float4 b) {
    uint4 r;
    r.x = pack2(a.x, a.y); r.y = pack2(a.z, a.w);
    r.z = pack2(b.x, b.y); r.w = pack2(b.z, b.w);
    return r;
}

__device__ __forceinline__ float dot2(unsigned int w, unsigned int h, float acc) {
#if __has_builtin(__builtin_amdgcn_fdot2)
    return __builtin_amdgcn_fdot2(__builtin_bit_cast(half2_t, w),
                                  __builtin_bit_cast(half2_t, h), acc, false);
#else
    half2_t wv = __builtin_bit_cast(half2_t, w), hv = __builtin_bit_cast(half2_t, h);
    return acc + (float)wv.x * (float)hv.x + (float)wv.y * (float)hv.y;
#endif
}

__device__ __forceinline__ float chunk_dot(const unsigned int* w4, uint4 h8, float acc) {
    acc = dot2(w4[0], h8.x, acc);
    acc = dot2(w4[1], h8.y, acc);
    acc = dot2(w4[2], h8.z, acc);
    acc = dot2(w4[3], h8.w, acc);
    return acc;
}

__global__ __attribute__((amdgpu_flat_work_group_size(NTHREADS, NTHREADS)))
           __attribute__((amdgpu_waves_per_eu(1, 1)))
void rnn_persist(
    const float* __restrict__ x, const float* __restrict__ h_init,
    const float* __restrict__ W_hx, const float* __restrict__ W_hh,
    const float* __restrict__ b_h, const float* __restrict__ W_ph,
    const float* __restrict__ b_p, float* __restrict__ out)
{
    __shared__ uint4 Wl[LDS_CHUNKS * HID];   // 64 KB: W chunks 56..63, [chunk][row]
    __shared__ uint4 hbuf[2][NCHUNK];        // 2 KB: h double buffer, f16
    __shared__ float x_s[T_SEQ];             // 4 KB: this column's inputs

    const int tid = threadIdx.x;
    const int b   = blockIdx.x;              // batch column
    const int r0  = tid, r1 = tid + NTHREADS;

    // Stage x column (coalesced).
    for (int i = tid; i < T_SEQ; i += NTHREADS) x_s[i] = x[(size_t)b * T_SEQ + i];

    const float whx0 = W_hx[r0], bh0 = b_h[r0];
    const float whx1 = W_hx[r1], bh1 = b_h[r1];

    ((_Float16*)hbuf[0])[r0] = (_Float16)h_init[r0];
    ((_Float16*)hbuf[0])[r1] = (_Float16)h_init[r1];

    // Pack this thread's two W rows: chunks 0..55 into registers.
    const float4* wrow0 = (const float4*)(W_hh + (size_t)r0 * HID);
    const float4* wrow1 = (const float4*)(W_hh + (size_t)r1 * HID);
    unsigned int wreg0[REG_CHUNKS * 4];
    unsigned int wreg1[REG_CHUNKS * 4];
    #pragma unroll
    for (int c = 0; c < REG_CHUNKS; ++c) {
        uint4 p0 = pack8(wrow0[2 * c], wrow0[2 * c + 1]);
        wreg0[4 * c + 0] = p0.x; wreg0[4 * c + 1] = p0.y;
        wreg0[4 * c + 2] = p0.z; wreg0[4 * c + 3] = p0.w;
        uint4 p1 = pack8(wrow1[2 * c], wrow1[2 * c + 1]);
        wreg1[4 * c + 0] = p1.x; wreg1[4 * c + 1] = p1.y;
        wreg1[4 * c + 2] = p1.z; wreg1[4 * c + 3] = p1.w;
    }
    // Chunks 56..63 into LDS, [chunk][row] so per-step reads are conflict-free.
    #pragma unroll
    for (int c = 0; c < LDS_CHUNKS; ++c) {
        int gc = REG_CHUNKS + c;
        Wl[c * HID + r0] = pack8(wrow0[2 * gc], wrow0[2 * gc + 1]);
        Wl[c * HID + r1] = pack8(wrow1[2 * gc], wrow1[2 * gc + 1]);
    }
    __syncthreads();

    float hv0 = 0.0f, hv1 = 0.0f;
    for (int t = 0; t < T_SEQ; ++t) {
        const int p = t & 1;
        // Double buffer => one barrier per step: separates last step's writes
        // (to hbuf[p]) from this step's reads of hbuf[p].
        __syncthreads();

        const float xw = x_s[t];
        float acc0[4] = {whx0 * xw + bh0, 0.0f, 0.0f, 0.0f};
        float acc1[4] = {whx1 * xw + bh1, 0.0f, 0.0f, 0.0f};
        const uint4* hb = hbuf[p];

        #pragma unroll
        for (int c = 0; c < REG_CHUNKS; ++c) {
            uint4 h8 = hb[c];                        // wave-uniform: LDS broadcast
            acc0[c & 3] = chunk_dot(&wreg0[4 * c], h8, acc0[c & 3]);
            acc1[c & 3] = chunk_dot(&wreg1[4 * c], h8, acc1[c & 3]);
        }
        #pragma unroll
        for (int c = 0; c < LDS_CHUNKS; ++c) {
            uint4 h8 = hb[REG_CHUNKS + c];
            uint4 w0 = Wl[c * HID + r0];             // lanes contiguous: no conflicts
            uint4 w1 = Wl[c * HID + r1];
            acc0[c & 3] = chunk_dot((const unsigned int*)&w0, h8, acc0[c & 3]);
            acc1[c & 3] = chunk_dot((const unsigned int*)&w1, h8, acc1[c & 3]);
        }
        float s0 = (acc0[0] + acc0[1]) + (acc0[2] + acc0[3]);
        float s1 = (acc1[0] + acc1[1]) + (acc1[2] + acc1[3]);

        // tanh(a) = 1 - 2/(e^{2a}+1)  (safe at +/-inf of exp)
        hv0 = 1.0f - 2.0f / (__expf(2.0f * s0) + 1.0f);
        hv1 = 1.0f - 2.0f / (__expf(2.0f * s1) + 1.0f);
        ((_Float16*)hbuf[1 - p])[r0] = (_Float16)hv0;
        ((_Float16*)hbuf[1 - p])[r1] = (_Float16)hv1;
    }

    // Epilogue: p = W_ph @ h_last + b_p for this column (f32 h in x_s).
    __syncthreads();
    x_s[r0] = hv0;
    x_s[r1] = hv1;
    __syncthreads();

    const int w = tid >> 6, lane = tid & 63;
    for (int c = w; c < NCLS; c += 4) {
        float s = 0.0f;
        #pragma unroll
        for (int j = 0; j < 8; ++j) {
            int r = lane + 64 * j;
            s += W_ph[c * HID + r] * x_s[r];
        }
        #pragma unroll
        for (int off = 32; off; off >>= 1) s += __shfl_down(s, off, 64);
        if (lane == 0) out[b * NCLS + c] = s + b_p[c];
    }
}

extern "C" void kernel_launch(void* const* d_in, const int* in_sizes, int n_in,
                              void* d_out, int out_size, void* d_ws, size_t ws_size,
                              hipStream_t stream) {
    const float* x      = (const float*)d_in[0];
    const float* h_init = (const float*)d_in[1];
    const float* W_hx   = (const float*)d_in[2];
    const float* W_hh   = (const float*)d_in[3];
    const float* b_h    = (const float*)d_in[4];
    const float* W_ph   = (const float*)d_in[5];
    const float* b_p    = (const float*)d_in[6];
    float* out = (float*)d_out;

    const int B = in_sizes[0] / T_SEQ;   // 256 batch columns -> 256 workgroups
    rnn_persist<<<B, NTHREADS, 0, stream>>>(x, h_init, W_hx, W_hh, b_h, W_ph, b_p, out);
}

// Round 3
// 2686.876 us; speedup vs baseline: 1.4253x; 1.4253x over previous
//
#include <hip/hip_runtime.h>

// VanillaRNN: h_{t+1} = tanh(W_hx x_t + W_hh h_t + b_h), T=1024, H=512, B=256.
// R3: one batch column per workgroup (256 wgs ~ 256 CUs), no inter-wg traffic.
// 512 threads (8 waves = 2/SIMD for latency hiding), one row per thread.
// Register budget pinned with amdgpu_waves_per_eu(2,2) => 256 VGPRs/thread:
//   - W_hh k in [0,448): f16 in VGPRs (224 regs/thread) -- zero-cost supply
//   - W_hh k in [448,512): f16 in LDS (64 KB), full-width conflict-free b128
//   - h: f16 double-buffered in LDS; uniform (broadcast) b128 reads, ~free
// No d_ws usage (workspace is uncached -> R1's hidden HBM saturation).
// No L2 streaming (f32 W at ~56 B/cyc/CU supplies too little to matter).
// 4 rotating accumulators -> 4 independent dot2 chains per thread.

#define T_SEQ      1024
#define HID        512
#define NTHREADS   512
#define NCLS       10
#define NCHUNK     64          // 64 chunks x 8 halfs = 512 k
#define REG_CHUNKS 56          // k in [0,448) in VGPRs (224 regs/thread)
#define LDS_CHUNKS 8           // k in [448,512) in LDS (64 KB)

typedef _Float16 half2_t __attribute__((ext_vector_type(2)));

__device__ __forceinline__ unsigned int pack2(float a, float b) {
    half2_t h = {(_Float16)a, (_Float16)b};
    return __builtin_bit_cast(unsigned int, h);
}

__device__ __forceinline__ uint4 pack8(float4 a, float4 b) {
    uint4 r;
    r.x = pack2(a.x, a.y); r.y = pack2(a.z, a.w);
    r.z = pack2(b.x, b.y); r.w = pack2(b.z, b.w);
    return r;
}

__device__ __forceinline__ float dot2(unsigned int w, unsigned int h, float acc) {
#if __has_builtin(__builtin_amdgcn_fdot2)
    return __builtin_amdgcn_fdot2(__builtin_bit_cast(half2_t, w),
                                  __builtin_bit_cast(half2_t, h), acc, false);
#else
    half2_t wv = __builtin_bit_cast(half2_t, w), hv = __builtin_bit_cast(half2_t, h);
    return acc + (float)wv.x * (float)hv.x + (float)wv.y * (float)hv.y;
#endif
}

__device__ __forceinline__ float chunk_dot(const unsigned int* w4, uint4 h8, float acc) {
    acc = dot2(w4[0], h8.x, acc);
    acc = dot2(w4[1], h8.y, acc);
    acc = dot2(w4[2], h8.z, acc);
    acc = dot2(w4[3], h8.w, acc);
    return acc;
}

__global__ __attribute__((amdgpu_flat_work_group_size(NTHREADS, NTHREADS)))
           __attribute__((amdgpu_waves_per_eu(2, 2)))
void rnn_persist(
    const float* __restrict__ x, const float* __restrict__ h_init,
    const float* __restrict__ W_hx, const float* __restrict__ W_hh,
    const float* __restrict__ b_h, const float* __restrict__ W_ph,
    const float* __restrict__ b_p, float* __restrict__ out)
{
    __shared__ uint4 Wl[LDS_CHUNKS * HID];   // 64 KB: W chunks 56..63, [chunk][row]
    __shared__ uint4 hbuf[2][NCHUNK];        // 2 KB: h double buffer, f16
    __shared__ float x_s[T_SEQ];             // 4 KB: this column's inputs

    const int tid = threadIdx.x;             // row
    const int b   = blockIdx.x;              // batch column

    // Stage x column (coalesced).
    for (int i = tid; i < T_SEQ; i += NTHREADS) x_s[i] = x[(size_t)b * T_SEQ + i];

    const float whx = W_hx[tid];
    const float bh  = b_h[tid];

    ((_Float16*)hbuf[0])[tid] = (_Float16)h_init[tid];

    // Pack this row of W_hh: chunks 0..55 into VGPRs (loads land directly in the
    // destination registers), chunks 56..63 into LDS at [chunk][row].
    const float4* wrow = (const float4*)(W_hh + (size_t)tid * HID);
    unsigned int wreg[REG_CHUNKS * 4];
    #pragma unroll
    for (int c = 0; c < REG_CHUNKS; ++c) {
        uint4 p = pack8(wrow[2 * c], wrow[2 * c + 1]);
        wreg[4 * c + 0] = p.x; wreg[4 * c + 1] = p.y;
        wreg[4 * c + 2] = p.z; wreg[4 * c + 3] = p.w;
    }
    #pragma unroll
    for (int c = 0; c < LDS_CHUNKS; ++c) {
        int gc = REG_CHUNKS + c;
        Wl[c * HID + tid] = pack8(wrow[2 * gc], wrow[2 * gc + 1]);
    }
    __syncthreads();

    float hval = 0.0f;
    for (int t = 0; t < T_SEQ; ++t) {
        const int p = t & 1;
        // Double buffer => one barrier per step (orders last step's h writes
        // before this step's h reads).
        __syncthreads();

        float acc[4];
        acc[0] = whx * x_s[t] + bh;
        acc[1] = 0.0f; acc[2] = 0.0f; acc[3] = 0.0f;
        const uint4* hb = hbuf[p];

        #pragma unroll
        for (int c = 0; c < REG_CHUNKS; ++c) {
            uint4 h8 = hb[c];                       // uniform addr: LDS broadcast
            acc[c & 3] = chunk_dot(&wreg[4 * c], h8, acc[c & 3]);
        }
        #pragma unroll
        for (int c = 0; c < LDS_CHUNKS; ++c) {
            uint4 h8 = hb[REG_CHUNKS + c];
            uint4 w8 = Wl[c * HID + tid];           // 64 lanes x 16 B: conflict-free
            acc[c & 3] = chunk_dot((const unsigned int*)&w8, h8, acc[c & 3]);
        }
        float s = (acc[0] + acc[1]) + (acc[2] + acc[3]);

        // tanh(a) = 1 - 2/(e^{2a}+1)  (exact at +/-inf of exp)
        hval = 1.0f - 2.0f / (__expf(2.0f * s) + 1.0f);
        ((_Float16*)hbuf[1 - p])[tid] = (_Float16)hval;
    }

    // Epilogue: p = W_ph @ h_last + b_p for this column (f32 h staged in x_s).
    __syncthreads();
    x_s[tid] = hval;
    __syncthreads();

    const int w = tid >> 6, lane = tid & 63;
    for (int c = w; c < NCLS; c += 8) {
        float s = 0.0f;
        #pragma unroll
        for (int j = 0; j < 8; ++j) {
            int r = lane + 64 * j;
            s += W_ph[c * HID + r] * x_s[r];
        }
        #pragma unroll
        for (int off = 32; off; off >>= 1) s += __shfl_down(s, off, 64);
        if (lane == 0) out[b * NCLS + c] = s + b_p[c];
    }
}

extern "C" void kernel_launch(void* const* d_in, const int* in_sizes, int n_in,
                              void* d_out, int out_size, void* d_ws, size_t ws_size,
                              hipStream_t stream) {
    const float* x      = (const float*)d_in[0];
    const float* h_init = (const float*)d_in[1];
    const float* W_hx   = (const float*)d_in[2];
    const float* W_hh   = (const float*)d_in[3];
    const float* b_h    = (const float*)d_in[4];
    const float* W_ph   = (const float*)d_in[5];
    const float* b_p    = (const float*)d_in[6];
    float* out = (float*)d_out;

    const int B = in_sizes[0] / T_SEQ;   // 256 batch columns -> 256 workgroups
    rnn_persist<<<B, NTHREADS, 0, stream>>>(x, h_init, W_hx, W_hh, b_h, W_ph, b_p, out);
}

// Round 4
// 1480.965 us; speedup vs baseline: 2.5858x; 1.8143x over previous
//
#include <hip/hip_runtime.h>

// VanillaRNN: h_{t+1} = tanh(W_hx x_t + W_hh h_t + b_h), T=1024, H=512, B=256.
// R4: K-sliced partial-sum decomposition. One batch column per WG (256 WGs).
// 512 threads = 8 waves. Wave w owns k-slice [64w,64w+64); lane l owns rows
// [8l,8l+8). Key property: wave w's h-slice h[64w..64w+64) is produced by wave
// w's OWN lanes (row r <-> thread r), so h never crosses waves -- no h
// broadcast through LDS (R3's 512 KB/step LDS wall). Only 8 f32 partial
// vectors cross waves (48 KB/step total LDS traffic for the reduction).
//   - W slice per thread: 8 rows x 32 f16-pairs; 28 pairs in VGPRs (224 regs),
//     4 pairs in LDS (64 KB, lane-stride-16B layout => conflict-free b128).
//   - LDS total 101 KB => 1 WG/CU => allocator budget = 2 waves/EU = 256 VGPRs.
//   - 8 independent dot2 chains (one per row) for issue-rate ILP.

#define T_SEQ    1024
#define HID      512
#define NTHREADS 512
#define NW       8            // waves
#define NCLS     10
#define RP       8            // rows per thread
#define PAIRS    32           // k-pairs per wave slice (64 k)
#define PREG     28           // pairs 0..27 in VGPRs
#define PLDS     4            // pairs 28..31 in LDS (one uint4 per (row,thread))

typedef _Float16 half2_t __attribute__((ext_vector_type(2)));

__device__ __forceinline__ unsigned int pack2(float a, float b) {
    half2_t h = {(_Float16)a, (_Float16)b};
    return __builtin_bit_cast(unsigned int, h);
}

__device__ __forceinline__ float dot2(unsigned int w, unsigned int h, float acc) {
#if __has_builtin(__builtin_amdgcn_fdot2)
    return __builtin_amdgcn_fdot2(__builtin_bit_cast(half2_t, w),
                                  __builtin_bit_cast(half2_t, h), acc, false);
#else
    half2_t wv = __builtin_bit_cast(half2_t, w), hv = __builtin_bit_cast(half2_t, h);
    return acc + (float)wv.x * (float)hv.x + (float)wv.y * (float)hv.y;
#endif
}

__global__ __attribute__((amdgpu_flat_work_group_size(NTHREADS, NTHREADS)))
           __attribute__((amdgpu_waves_per_eu(2, 2)))
void rnn_persist(
    const float* __restrict__ x, const float* __restrict__ h_init,
    const float* __restrict__ W_hx, const float* __restrict__ W_hh,
    const float* __restrict__ b_h, const float* __restrict__ W_ph,
    const float* __restrict__ b_p, float* __restrict__ out)
{
    __shared__ uint4  Wl[NW * RP * 64];        // 64 KB: pairs 28..31, [w][r'][lane]
    __shared__ float  part[2][NW][HID];        // 32 KB: partial sums, double-buffered
    __shared__ float  x_s[T_SEQ];              //  4 KB
    __shared__ _Float16 hs[HID];               //  1 KB: h (f16); hs[64w+j] = wave w's slice

    const int tid  = threadIdx.x;
    const int b    = blockIdx.x;
    const int w    = tid >> 6;                 // wave = k-slice owner
    const int lane = tid & 63;

    // Stage x column (coalesced).
    for (int i = tid; i < T_SEQ; i += NTHREADS) x_s[i] = x[(size_t)b * T_SEQ + i];

    const float whx = W_hx[tid];               // thread owns output row `tid`
    const float bh  = b_h[tid];
    hs[tid] = (_Float16)h_init[tid];

    // Load W slice: rows 8*lane..8*lane+8, cols [64w, 64w+64).
    unsigned int wreg[RP][PREG];               // 224 VGPRs
    #pragma unroll
    for (int r = 0; r < RP; ++r) {
        const float4* row = (const float4*)(W_hh + (size_t)(RP * lane + r) * HID + 64 * w);
        unsigned int p32[PAIRS];
        #pragma unroll
        for (int q = 0; q < 16; ++q) {         // 16 float4 = 64 floats = 32 pairs
            float4 v = row[q];
            p32[2 * q]     = pack2(v.x, v.y);
            p32[2 * q + 1] = pack2(v.z, v.w);
        }
        #pragma unroll
        for (int p = 0; p < PREG; ++p) wreg[r][p] = p32[p];
        Wl[(w * RP + r) * 64 + lane] = make_uint4(p32[28], p32[29], p32[30], p32[31]);
    }
    __syncthreads();

    const unsigned int* hsw = (const unsigned int*)hs + w * (PAIRS);  // 32 pairs of slice

    float hval = 0.0f;
    for (int t = 0; t < T_SEQ; ++t) {
        const int buf = t & 1;

        float acc[RP];
        #pragma unroll
        for (int r = 0; r < RP; ++r) acc[r] = 0.0f;

        // Pairs 0..27 from registers; h pair is a wave-uniform LDS b32 (cheap).
        #pragma unroll
        for (int p = 0; p < PREG; ++p) {
            unsigned int hp = hsw[p];
            #pragma unroll
            for (int r = 0; r < RP; ++r) acc[r] = dot2(wreg[r][p], hp, acc[r]);
        }
        // Pairs 28..31 from LDS (conflict-free b128: lane-stride 16 B).
        {
            unsigned int h0 = hsw[28], h1 = hsw[29], h2 = hsw[30], h3 = hsw[31];
            #pragma unroll
            for (int r = 0; r < RP; ++r) {
                uint4 wq = Wl[(w * RP + r) * 64 + lane];
                acc[r] = dot2(wq.x, h0, acc[r]);
                acc[r] = dot2(wq.y, h1, acc[r]);
                acc[r] = dot2(wq.z, h2, acc[r]);
                acc[r] = dot2(wq.w, h3, acc[r]);
            }
        }

        // Write partials for rows 8*lane..8*lane+8 (two contiguous float4).
        float4* pw = (float4*)&part[buf][w][RP * lane];
        pw[0] = make_float4(acc[0], acc[1], acc[2], acc[3]);
        pw[1] = make_float4(acc[4], acc[5], acc[6], acc[7]);

        __syncthreads();   // partials visible; dbuf makes one barrier/step safe

        // Reduce: thread `tid` owns row `tid`.
        float s = whx * x_s[t] + bh;
        #pragma unroll
        for (int j = 0; j < NW; ++j) s += part[buf][j][tid];

        // tanh(a) = 1 - 2/(e^{2a}+1)  (exact at +/-inf of exp)
        hval = 1.0f - 2.0f / (__expf(2.0f * s) + 1.0f);
        hs[tid] = (_Float16)hval;   // consumed only by this thread's own wave
    }

    // Epilogue: p = W_ph @ h_last + b_p (h_last f32 staged in x_s).
    __syncthreads();
    x_s[tid] = hval;
    __syncthreads();

    for (int c = w; c < NCLS; c += NW) {
        float s = 0.0f;
        #pragma unroll
        for (int j = 0; j < 8; ++j) {
            int r = lane + 64 * j;
            s += W_ph[c * HID + r] * x_s[r];
        }
        #pragma unroll
        for (int off = 32; off; off >>= 1) s += __shfl_down(s, off, 64);
        if (lane == 0) out[b * NCLS + c] = s + b_p[c];
    }
}

extern "C" void kernel_launch(void* const* d_in, const int* in_sizes, int n_in,
                              void* d_out, int out_size, void* d_ws, size_t ws_size,
                              hipStream_t stream) {
    const float* x      = (const float*)d_in[0];
    const float* h_init = (const float*)d_in[1];
    const float* W_hx   = (const float*)d_in[2];
    const float* W_hh   = (const float*)d_in[3];
    const float* b_h    = (const float*)d_in[4];
    const float* W_ph   = (const float*)d_in[5];
    const float* b_p    = (const float*)d_in[6];
    float* out = (float*)d_out;

    const int B = in_sizes[0] / T_SEQ;   // 256 batch columns -> 256 workgroups
    rnn_persist<<<B, NTHREADS, 0, stream>>>(x, h_init, W_hx, W_hh, b_h, W_ph, b_p, out);
}